// Round 5
// baseline (74.377 us; speedup 1.0000x reference)
//
#include <hip/hip_runtime.h>
#include <hip/hip_bf16.h>

#define TDEPTH 6
#define NLEAF 64
#define NGATE 63
#define INF 512
#define OUTF 512
#define BATCH 1024

#define BM 128
#define BN 64
#define SPLITK 16
#define KCH 513     // 512 real i-chunks + 1 virtual bias chunk (x==1, W=pb)
#define THREADS 256
#define XPITCH 36   // f32 pitch for x rows (144B)
#define BPITCH 144  // byte pitch for B LDS rows (128B data + 16B pad)

typedef __attribute__((ext_vector_type(4)))  float f32x4;
typedef __attribute__((ext_vector_type(16))) float f32x16;
typedef __attribute__((ext_vector_type(8)))  __bf16 bf16x8;

// ---------------- kernel 1: leaf probabilities ----------------
__global__ __launch_bounds__(256) void leaf_kernel(
    const float* __restrict__ x, const float* __restrict__ gw,
    const float* __restrict__ gb, float* __restrict__ leaf) {
  const int wid = threadIdx.x >> 6, lane = threadIdx.x & 63;
  const int b = blockIdx.x * 4 + wid;
  __shared__ float g[4][NLEAF];
  if (lane < NGATE) {
    const float* xr = x + (size_t)b * INF;
    float a0 = 0.f, a1 = 0.f, a2 = 0.f, a3 = 0.f;
    #pragma unroll 4
    for (int i = 0; i < INF; i += 4) {
      a0 += xr[i + 0] * gw[(i + 0) * NGATE + lane];
      a1 += xr[i + 1] * gw[(i + 1) * NGATE + lane];
      a2 += xr[i + 2] * gw[(i + 2) * NGATE + lane];
      a3 += xr[i + 3] * gw[(i + 3) * NGATE + lane];
    }
    float t = (a0 + a1) + (a2 + a3) + gb[lane];
    g[wid][lane] = 1.0f / (1.0f + __expf(-t));
  }
  __syncthreads();
  float p = 1.0f;
  #pragma unroll
  for (int d = 0; d < TDEPTH; d++) {
    int prefix = lane >> (TDEPTH - 1 - d);
    int node = (1 << d) - 1 + (prefix >> 1);
    float gv = g[wid][node];
    p *= (prefix & 1) ? (1.0f - gv) : gv;
  }
  leaf[(size_t)b * NLEAF + lane] = p;
}

// raw barrier: lgkm drain only — global prefetch stays in flight
__device__ __forceinline__ void sync_raw() {
  asm volatile("s_waitcnt lgkmcnt(0)" ::: "memory");
  __builtin_amdgcn_sched_barrier(0);
  __builtin_amdgcn_s_barrier();
  __builtin_amdgcn_sched_barrier(0);
}

// ---------------- kernel 2: fused GEMM, 32x32x16 MFMA ----------------
// Wave tile 32m x 64o. A built in regs: lane row = lane&31, k-half = lane>>5;
// lf = 32 resident leaf f32; one x scalar per step. B staged to padded LDS.
__global__ __launch_bounds__(THREADS, 4) void gemm_kernel(
    const float* __restrict__ x, const float* __restrict__ pw,
    const float* __restrict__ pb, const float* __restrict__ leaf,
    float* __restrict__ partial) {
  __shared__ __align__(16) float xsm[BM * XPITCH];          // 18 KB
  __shared__ __align__(16) __bf16 Bsm[2][BN * (BPITCH/2)];  // 2 x 9 KB

  const int tid = threadIdx.x;
  const int lane = tid & 63;
  const int wid = tid >> 6;           // 4 waves, each 32 m-rows
  const int lo = lane & 31;           // MFMA row/col index
  const int half = lane >> 5;         // k-half select

  // bid decomposition: nb = bid&7 -> all 8 mb-sharers of a B-slice on one XCD
  const int bid = blockIdx.x;
  const int nb = bid & 7, mb = (bid >> 3) & 7, s = bid >> 6;
  const int m0 = mb * BM, n0 = nb * BN;
  const int cs = (s * KCH) / SPLITK;
  const int ce = ((s + 1) * KCH) / SPLITK;
  const int nreal = min(ce, INF) - cs;
  const int total = nreal + ((ce == KCH) ? 1 : 0);   // bias step only on s=15

  const int xrow = wid * 32 + lo;     // this lane's m-row within the block

  // resident leaf fragment: 4 k-chunks x 8 f32 (this lane's half)
  f32x4 lf[4][2];
  {
    const float* lr = leaf + (size_t)(m0 + xrow) * NLEAF + half * 8;
    #pragma unroll
    for (int t4 = 0; t4 < 4; t4++) {
      lf[t4][0] = *(const f32x4*)(lr + t4 * 16);
      lf[t4][1] = *(const f32x4*)(lr + t4 * 16 + 4);
    }
  }

  // stage x slice: 128 rows x 32 i (f32), padded pitch
  {
    int r = tid >> 1, h = tid & 1;
    const float* src = x + (size_t)(m0 + r) * INF + cs + h * 16;
    float* dst = xsm + r * XPITCH + h * 16;
    #pragma unroll
    for (int j = 0; j < 4; j++)
      *(f32x4*)(dst + j * 4) = *(const f32x4*)(src + j * 4);
  }

  // B staging assignment: thread -> (row bo, 64B-contiguous quarter bc)
  const int bo = tid >> 2, bc = tid & 3;
  const float* pwrow = pw + (size_t)(n0 + bo) * (INF * NLEAF) + bc * 16;
  const float* pbrow = pb + (size_t)(n0 + bo) * NLEAF + bc * 16;

  f32x16 acc0 = (f32x16)(0.f), acc1 = (f32x16)(0.f);

  f32x4 bv[4];
  // prologue: load + write plane 0
  {
    const float* sp = pwrow + (size_t)cs * NLEAF;
    #pragma unroll
    for (int j = 0; j < 4; j++) bv[j] = *(const f32x4*)(sp + j * 4);
    #pragma unroll
    for (int h = 0; h < 2; h++) {
      f32x4 a = bv[2 * h], b = bv[2 * h + 1];
      bf16x8 w;
      w[0] = (__bf16)a[0]; w[1] = (__bf16)a[1];
      w[2] = (__bf16)a[2]; w[3] = (__bf16)a[3];
      w[4] = (__bf16)b[0]; w[5] = (__bf16)b[1];
      w[6] = (__bf16)b[2]; w[7] = (__bf16)b[3];
      *(bf16x8*)((char*)&Bsm[0][0] + bo * BPITCH + bc * 32 + h * 16) = w;
    }
  }
  sync_raw();

  __bf16* cur = &Bsm[0][0];
  __bf16* nxt = &Bsm[1][0];
  for (int t = 0; t < total; ++t) {
    // (1) prefetch next plane into regs (in flight across the MFMA burst)
    const bool more = (t + 1 < total);
    if (more) {
      const float* sp = (t + 1 < nreal)
          ? pwrow + (size_t)(cs + t + 1) * NLEAF : pbrow;
      #pragma unroll
      for (int j = 0; j < 4; j++) bv[j] = *(const f32x4*)(sp + j * 4);
    }
    // (2) A-frags: one x scalar, 32 muls, 16 cvt_pk
    float xvr = xsm[xrow * XPITCH + (t & 31)];
    float xv = (t < nreal) ? xvr : 1.0f;
    bf16x8 afr[4];
    #pragma unroll
    for (int t4 = 0; t4 < 4; t4++) {
      f32x4 p0 = lf[t4][0] * xv, p1 = lf[t4][1] * xv;
      bf16x8 a;
      a[0] = (__bf16)p0[0]; a[1] = (__bf16)p0[1];
      a[2] = (__bf16)p0[2]; a[3] = (__bf16)p0[3];
      a[4] = (__bf16)p1[0]; a[5] = (__bf16)p1[1];
      a[6] = (__bf16)p1[2]; a[7] = (__bf16)p1[3];
      afr[t4] = a;
    }
    // (3) B-frags from LDS + 8 MFMAs (two independent acc chains)
    #pragma unroll
    for (int t4 = 0; t4 < 4; t4++) {
      bf16x8 b0 = *(const bf16x8*)((const char*)cur + lo * BPITCH +
                                   t4 * 32 + half * 16);
      bf16x8 b1 = *(const bf16x8*)((const char*)cur + (32 + lo) * BPITCH +
                                   t4 * 32 + half * 16);
      acc0 = __builtin_amdgcn_mfma_f32_32x32x16_bf16(afr[t4], b0, acc0, 0, 0, 0);
      acc1 = __builtin_amdgcn_mfma_f32_32x32x16_bf16(afr[t4], b1, acc1, 0, 0, 0);
    }
    // (4) cvt + write next plane
    if (more) {
      #pragma unroll
      for (int h = 0; h < 2; h++) {
        f32x4 a = bv[2 * h], b = bv[2 * h + 1];
        bf16x8 w;
        w[0] = (__bf16)a[0]; w[1] = (__bf16)a[1];
        w[2] = (__bf16)a[2]; w[3] = (__bf16)a[3];
        w[4] = (__bf16)b[0]; w[5] = (__bf16)b[1];
        w[6] = (__bf16)b[2]; w[7] = (__bf16)b[3];
        *(bf16x8*)((char*)nxt + bo * BPITCH + bc * 32 + h * 16) = w;
      }
    }
    sync_raw();
    __bf16* tmp = cur; cur = nxt; nxt = tmp;
  }

  // epilogue: D row = (reg&3) + 8*(reg>>2) + 4*half (m74/m101), col = lo
  float* dst = partial + ((size_t)s * BATCH + m0 + wid * 32) * OUTF + n0;
  #pragma unroll
  for (int e = 0; e < 16; e++) {
    int row = (e & 3) + 8 * (e >> 2) + 4 * half;
    dst[(size_t)row * OUTF + lo] = acc0[e];
    dst[(size_t)row * OUTF + 32 + lo] = acc1[e];
  }
}

// ---------------- kernel 3: split-K reduce ----------------
__global__ __launch_bounds__(256) void reduce_kernel(
    const float* __restrict__ partial, float* __restrict__ out) {
  size_t e = ((size_t)blockIdx.x * 256 + threadIdx.x) * 4;
  f32x4 sum = (f32x4){0.f, 0.f, 0.f, 0.f};
  #pragma unroll
  for (int s = 0; s < SPLITK; s++)
    sum += *(const f32x4*)(partial + (size_t)s * BATCH * OUTF + e);
  *(f32x4*)(out + e) = sum;
}

extern "C" void kernel_launch(void* const* d_in, const int* in_sizes, int n_in,
                              void* d_out, int out_size, void* d_ws, size_t ws_size,
                              hipStream_t stream) {
  const float* x  = (const float*)d_in[0];
  const float* gw = (const float*)d_in[1];
  const float* gb = (const float*)d_in[2];
  const float* pw = (const float*)d_in[3];
  const float* pb = (const float*)d_in[4];
  float* out = (float*)d_out;

  float* leaf    = (float*)d_ws;                       // 256 KB
  float* partial = (float*)((char*)d_ws + (1 << 19));  // 16 x 2 MB

  leaf_kernel<<<BATCH / 4, 256, 0, stream>>>(x, gw, gb, leaf);
  gemm_kernel<<<(BATCH / BM) * (OUTF / BN) * SPLITK, THREADS, 0, stream>>>(
      x, pw, pb, leaf, partial);
  reduce_kernel<<<(BATCH * OUTF) / (256 * 4), 256, 0, stream>>>(partial, out);
}